// Round 6
// baseline (8097.190 us; speedup 1.0000x reference)
//
#include <hip/hip_runtime.h>

// voltageNN: 2-layer LSTM (H=256, P=1, in=1), T=1000, B=16384, + MLP head.
// One wave per 2 batch elements; lane owns units u = lane + 64k (k=0..3) for
// both layers, processed as packed pairs on float2 (v_pk_*_f32).
// Round-5 changes vs round-4:
//  (a) weights PINNED in VGPRs via asm barriers (round-4 FETCH_SIZE=34GB showed
//      the compiler re-loaded all weights from memory every iteration),
//  (b) all activations via exact Pade continued-fraction rationals -> only
//      2 rcp per unit-pair per step, ZERO exp2 (was 10 exp2 + 2 rcp).
//      sigma(z) = (0.5*Q + (z/2)*P)/Q,  P,Q = tanh CF [5/4] at u=z/2
//      tanh(z)  = z*P(z^2)/Q(z^2),      CF depth-13 [7/6]
//      c' = f*c + i*g and o*tanh(c')*wr assembled over common denominators.

#define T_LEN 1000
#define WAVES 4     // waves per block
#define BPW   2     // batch elements per wave

typedef float v2f __attribute__((ext_vector_type(2)));

static __device__ __forceinline__ float rcpr(float x) { return __builtin_amdgcn_rcpf(x); }
static __device__ __forceinline__ v2f fma2(v2f a, v2f b, v2f c) {
    return __builtin_elementwise_fma(a, b, c);
}
static __device__ __forceinline__ v2f splat2(float s) { v2f r; r.x = s; r.y = s; return r; }
static __device__ __forceinline__ v2f swap2(v2f a) { return __builtin_shufflevector(a, a, 1, 0); }

template<int CTRL>
static __device__ __forceinline__ float dpp0(float x) {
    return __int_as_float(__builtin_amdgcn_update_dpp(
        0, __float_as_int(x), CTRL, 0xf, 0xf, true));
}
// sum across 64 lanes; result valid in lane 63
static __device__ __forceinline__ float wave_sum63(float x) {
    x += dpp0<0x111>(x);   // row_shr:1
    x += dpp0<0x112>(x);   // row_shr:2
    x += dpp0<0x114>(x);   // row_shr:4
    x += dpp0<0x118>(x);   // row_shr:8
    x += dpp0<0x142>(x);   // row_bcast:15
    x += dpp0<0x143>(x);   // row_bcast:31
    return x;
}
static __device__ __forceinline__ float lane63(float x) {
    return __int_as_float(__builtin_amdgcn_readlane(__float_as_int(x), 63));
}
static __device__ __forceinline__ float rdlane(float x, int l) {
    return __int_as_float(__builtin_amdgcn_readlane(__float_as_int(x), l));
}

// ---- Pade coefficients (exact, from tanh continued fraction) ----
// sigma core [5/4]:  P/945 = 0.5 + v/18 + v^2/1890 (0.5 folded), Q/945 = 1 + 4v/9 + v^2/63
#define SP2 5.2910053e-04f
#define SP1 5.5555556e-02f
#define SQ2 1.5873017e-02f
#define SQ1 4.4444445e-01f
// tanh [7/6]: P/135135 = 1 + 5v/39 + 2v^2/715 + v^3/135135
//             Q/135135 = 1 + 6v/13 + 10v^2/429 + 4v^3/19305
#define TP3 7.3999408e-06f
#define TP2 2.7972028e-03f
#define TP1 1.2820513e-01f
#define TQ3 2.0720021e-04f
#define TQ2 2.3310023e-02f
#define TQ1 4.6153846e-01f

// sigma(2u) as rational N/Q (u = z/2 pre-scaled into weights)
static __device__ __forceinline__ void sig_rat(v2f u, v2f& N, v2f& Q) {
    v2f v = u * u;
    v2f p = fma2(v, splat2(SP2), splat2(SP1));
    p = fma2(p, v, splat2(0.5f));
    Q = fma2(fma2(v, splat2(SQ2), splat2(SQ1)), v, splat2(1.0f));
    N = fma2(Q, splat2(0.5f), u * p);
}
// tanh(z) as rational N/Q
static __device__ __forceinline__ void tanh_rat(v2f z, v2f& N, v2f& Q) {
    v2f v = z * z;
    v2f p = fma2(v, splat2(TP3), splat2(TP2));
    p = fma2(p, v, splat2(TP1));
    p = fma2(p, v, splat2(1.0f));
    Q = fma2(fma2(fma2(v, splat2(TQ3), splat2(TQ2)), v, splat2(TQ1)), v, splat2(1.0f));
    N = z * p;
}

struct CellW {
    v2f wi[2], wf[2], wg[2], wo[2];   // input weights (sigma gates prescaled x0.5)
    v2f vi[2], vf[2], vg[2], vo[2];   // recurrent weights
    v2f bi[2], bf[2], bg[2], bo[2];   // biases (bih+bhh)
    v2f wr[2];                        // projection row
};

static __device__ __forceinline__ void load_w(CellW& W, int lane,
        const float* __restrict__ Wih, const float* __restrict__ Whh,
        const float* __restrict__ bih, const float* __restrict__ bhh,
        const float* __restrict__ Whr) {
#pragma unroll
    for (int p = 0; p < 2; ++p) {
        int ua = lane + 128 * p;
        int ub = ua + 64;
        v2f t;
        t.x = Wih[ua];        t.y = Wih[ub];        W.wi[p] = t * 0.5f;
        t.x = Wih[256 + ua];  t.y = Wih[256 + ub];  W.wf[p] = t * 0.5f;
        t.x = Wih[512 + ua];  t.y = Wih[512 + ub];  W.wg[p] = t;
        t.x = Wih[768 + ua];  t.y = Wih[768 + ub];  W.wo[p] = t * 0.5f;
        t.x = Whh[ua];        t.y = Whh[ub];        W.vi[p] = t * 0.5f;
        t.x = Whh[256 + ua];  t.y = Whh[256 + ub];  W.vf[p] = t * 0.5f;
        t.x = Whh[512 + ua];  t.y = Whh[512 + ub];  W.vg[p] = t;
        t.x = Whh[768 + ua];  t.y = Whh[768 + ub];  W.vo[p] = t * 0.5f;
        t.x = bih[ua] + bhh[ua];
        t.y = bih[ub] + bhh[ub];                    W.bi[p] = t * 0.5f;
        t.x = bih[256 + ua] + bhh[256 + ua];
        t.y = bih[256 + ub] + bhh[256 + ub];        W.bf[p] = t * 0.5f;
        t.x = bih[512 + ua] + bhh[512 + ua];
        t.y = bih[512 + ub] + bhh[512 + ub];        W.bg[p] = t;
        t.x = bih[768 + ua] + bhh[768 + ua];
        t.y = bih[768 + ub] + bhh[768 + ub];        W.bo[p] = t * 0.5f;
        t.x = Whr[ua];        t.y = Whr[ub];        W.wr[p] = t;
    }
}

// Pin weight values in VGPRs: asm results cannot be rematerialized-by-reload.
#define PIN(x) asm volatile("" : "+v"(x))
static __device__ __forceinline__ void pin_w(CellW& W) {
#pragma unroll
    for (int p = 0; p < 2; ++p) {
        PIN(W.wi[p]); PIN(W.wf[p]); PIN(W.wg[p]); PIN(W.wo[p]);
        PIN(W.vi[p]); PIN(W.vf[p]); PIN(W.vg[p]); PIN(W.vo[p]);
        PIN(W.bi[p]); PIN(W.bf[p]); PIN(W.bg[p]); PIN(W.bo[p]);
        PIN(W.wr[p]);
    }
}

// One LSTM cell step for this lane's 4 units (2 packed pairs). x,h wave-uniform.
static __device__ __forceinline__ float cell(const CellW& W, float x, float h,
                                             v2f (&c)[2]) {
    const v2f xs = splat2(x);
    const v2f hs = splat2(h);
    float s = 0.0f;
#pragma unroll
    for (int p = 0; p < 2; ++p) {
        v2f ui = fma2(xs, W.wi[p], fma2(hs, W.vi[p], W.bi[p]));  // z_i/2
        v2f uf = fma2(xs, W.wf[p], fma2(hs, W.vf[p], W.bf[p]));
        v2f uo = fma2(xs, W.wo[p], fma2(hs, W.vo[p], W.bo[p]));
        v2f zg = fma2(xs, W.wg[p], fma2(hs, W.vg[p], W.bg[p]));
        v2f Ni, Qi, Nf, Qf, No, Qo, Ng, Qg;
        sig_rat(ui, Ni, Qi);
        sig_rat(uf, Nf, Qf);
        sig_rat(uo, No, Qo);
        tanh_rat(zg, Ng, Qg);
        // cn = f*c + i*g over common denominator Qf*Qi*Qg  (all Q >= 1)
        v2f A   = Qi * Qg;
        v2f NUM = fma2(Ni * Ng, Qf, (Nf * c[p]) * A);
        v2f DEN = A * Qf;
        float r = rcpr(DEN.x * DEN.y);            // merged rcp (2 units)
        v2f cn  = (NUM * swap2(DEN)) * splat2(r);
        c[p] = cn;
        // s += o * tanh(cn) * wr  over common denominator Qo*Qt
        v2f Nt, Qt;
        tanh_rat(cn, Nt, Qt);
        v2f t3 = (Nt * No) * W.wr[p];
        v2f D2 = Qo * Qt;
        float r2 = rcpr(D2.x * D2.y);             // merged rcp (2 units)
        v2f t4 = t3 * swap2(D2);
        s = fmaf(t4.x + t4.y, r2, s);
    }
    return s;
}

__global__ __launch_bounds__(256, 2)
void voltage_lstm_kernel(const float* __restrict__ x,
        const float* __restrict__ Wih0, const float* __restrict__ Whh0,
        const float* __restrict__ bih0, const float* __restrict__ bhh0,
        const float* __restrict__ Whr0,
        const float* __restrict__ Wih1, const float* __restrict__ Whh1,
        const float* __restrict__ bih1, const float* __restrict__ bhh1,
        const float* __restrict__ Whr1,
        const float* __restrict__ W1, const float* __restrict__ b1p,
        const float* __restrict__ W2, const float* __restrict__ b2,
        float* __restrict__ out)
{
    __shared__ __align__(16) float h1buf[WAVES][BPW][T_LEN];

    const int lane = threadIdx.x & 63;
    const int wv   = threadIdx.x >> 6;
    const int w    = blockIdx.x * WAVES + wv;
    const int bA   = w * BPW;
    const int bB   = bA + 1;

    CellW W0c, W1c;
    load_w(W0c, lane, Wih0, Whh0, bih0, bhh0, Whr0);
    load_w(W1c, lane, Wih1, Whh1, bih1, bhh1, Whr1);
    pin_w(W0c);
    pin_w(W1c);

    v2f c0A[2], c0B[2], c1A[2], c1B[2];
#pragma unroll
    for (int p = 0; p < 2; ++p) {
        c0A[p] = splat2(0.f); c0B[p] = splat2(0.f);
        c1A[p] = splat2(0.f); c1B[p] = splat2(0.f);
    }

    const float* xA = x + (long)bA * T_LEN;
    const float* xB = x + (long)bB * T_LEN;
    float xcA = xA[lane];              // x chunk for t in [0,64)
    float xcB = xB[lane];

    // --- prologue: layer0 step 0 (h0=0) ---
    float h0A, h0B, h1A = 0.0f, h1B = 0.0f;
    {
        float xtA = rdlane(xcA, 0), xtB = rdlane(xcB, 0);
        float sA = wave_sum63(cell(W0c, xtA, 0.0f, c0A));
        float sB = wave_sum63(cell(W0c, xtB, 0.0f, c0B));
        h0A = lane63(sA);
        h0B = lane63(sB);
    }

    // --- main loop: iter j computes layer0 step j+1 AND layer1 step j
    // (4 independent cell chains across 2 batches -> ILP).
    for (int j = 0; j < T_LEN - 1; ++j) {
        const int idx = j + 1;
        if ((idx & 63) == 0) {
            int tl = idx + lane;
            xcA = (tl < T_LEN) ? xA[tl] : 0.0f;
            xcB = (tl < T_LEN) ? xB[tl] : 0.0f;
        }
        float xtA = rdlane(xcA, idx & 63);
        float xtB = rdlane(xcB, idx & 63);

        float a0A = cell(W0c, xtA, h0A, c0A);
        float a0B = cell(W0c, xtB, h0B, c0B);
        float a1A = cell(W1c, h0A, h1A, c1A);
        float a1B = cell(W1c, h0B, h1B, c1B);

        a0A = wave_sum63(a0A);
        a0B = wave_sum63(a0B);
        a1A = wave_sum63(a1A);
        a1B = wave_sum63(a1B);

        if (lane == 63) {
            h1buf[wv][0][j] = a1A;
            h1buf[wv][1][j] = a1B;
        }
        h0A = lane63(a0A);  h0B = lane63(a0B);
        h1A = lane63(a1A);  h1B = lane63(a1B);
    }
    // --- epilogue: layer1 step T-1 ---
    {
        float a1A = wave_sum63(cell(W1c, h0A, h1A, c1A));
        float a1B = wave_sum63(cell(W1c, h0B, h1B, c1B));
        if (lane == 63) {
            h1buf[wv][0][T_LEN - 1] = a1A;
            h1buf[wv][1][T_LEN - 1] = a1B;
        }
    }
    __syncthreads();

    // --- head: relu(h1 @ W1^T + b1) @ W2^T + b2 for both batches ---
    const float* hA = h1buf[wv][0];
    const float* hB = h1buf[wv][1];
    const int j0 = lane;                 // rows 0..63
    const int j1 = lane + 64;            // rows 64..99 (lanes 0..35)
    const bool has1 = (j1 < 100);
    const float* r0 = W1 + j0 * T_LEN;
    const float* r1 = W1 + (has1 ? j1 : 0) * T_LEN;
    float aA0 = 0.f, aA1 = 0.f, aB0 = 0.f, aB1 = 0.f;
    for (int t = 0; t < T_LEN; t += 4) {
        float4 u0 = *(const float4*)(r0 + t);
        float4 u1 = *(const float4*)(r1 + t);
        float4 pA = *(const float4*)(hA + t);
        float4 pB = *(const float4*)(hB + t);
        aA0 = fmaf(u0.x, pA.x, aA0); aA0 = fmaf(u0.y, pA.y, aA0);
        aA0 = fmaf(u0.z, pA.z, aA0); aA0 = fmaf(u0.w, pA.w, aA0);
        aA1 = fmaf(u1.x, pA.x, aA1); aA1 = fmaf(u1.y, pA.y, aA1);
        aA1 = fmaf(u1.z, pA.z, aA1); aA1 = fmaf(u1.w, pA.w, aA1);
        aB0 = fmaf(u0.x, pB.x, aB0); aB0 = fmaf(u0.y, pB.y, aB0);
        aB0 = fmaf(u0.z, pB.z, aB0); aB0 = fmaf(u0.w, pB.w, aB0);
        aB1 = fmaf(u1.x, pB.x, aB1); aB1 = fmaf(u1.y, pB.y, aB1);
        aB1 = fmaf(u1.z, pB.z, aB1); aB1 = fmaf(u1.w, pB.w, aB1);
    }
    float bb0 = b1p[j0],   w20 = W2[j0];
    float bb1 = has1 ? b1p[j1] : 0.f;
    float w21 = has1 ? W2[j1]  : 0.f;
    float sA = fmaxf(aA0 + bb0, 0.f) * w20;
    float sB = fmaxf(aB0 + bb0, 0.f) * w20;
    if (has1) {
        sA = fmaf(fmaxf(aA1 + bb1, 0.f), w21, sA);
        sB = fmaf(fmaxf(aB1 + bb1, 0.f), w21, sB);
    }
    sA = wave_sum63(sA);
    sB = wave_sum63(sB);
    if (lane == 63) {
        float bias2 = b2[0];
        out[bA] = sA + bias2;
        out[bB] = sB + bias2;
    }
}

extern "C" void kernel_launch(void* const* d_in, const int* in_sizes, int n_in,
                              void* d_out, int out_size, void* d_ws, size_t ws_size,
                              hipStream_t stream) {
    (void)in_sizes; (void)n_in; (void)d_ws; (void)ws_size; (void)out_size;
    const float* x    = (const float*)d_in[0];
    const float* Wih0 = (const float*)d_in[1];
    const float* Whh0 = (const float*)d_in[2];
    const float* bih0 = (const float*)d_in[3];
    const float* bhh0 = (const float*)d_in[4];
    const float* Whr0 = (const float*)d_in[5];
    const float* Wih1 = (const float*)d_in[6];
    const float* Whh1 = (const float*)d_in[7];
    const float* bih1 = (const float*)d_in[8];
    const float* bhh1 = (const float*)d_in[9];
    const float* Whr1 = (const float*)d_in[10];
    const float* W1   = (const float*)d_in[11];
    const float* b1   = (const float*)d_in[12];
    const float* W2   = (const float*)d_in[13];
    const float* b2   = (const float*)d_in[14];
    float* outp = (float*)d_out;

    dim3 grid(16384 / (WAVES * BPW)), block(256);
    voltage_lstm_kernel<<<grid, block, 0, stream>>>(
        x, Wih0, Whh0, bih0, bhh0, Whr0,
        Wih1, Whh1, bih1, bhh1, Whr1,
        W1, b1, W2, b2, outp);
}

// Round 7
// 6409.552 us; speedup vs baseline: 1.2633x; 1.2633x over previous
//
#include <hip/hip_runtime.h>

// voltageNN: 2-layer LSTM (H=256, P=1, in=1), T=1000, B=16384, + MLP head.
// One wave per 2 batch elements; lane owns units u = lane + 64k (k=0..3) for
// both layers, processed as PACKED pairs on float2 (v_pk_*_f32).
// Recurrent scalars via readlane (SGPR); reduction via DPP shr-tree (no LDS).
// Trans budget: 6/unit-step (5 exp2 + 1 merged rcp) via common-denominator:
//   sigma(z)=1/(1+I), I=2^(-L2E z); tanh(z)=(G-1)/(G+1), G=2^(2 L2E z)
//   cn = [u*c + (G-1)(1+F)] / [(1+F)*u],  u=(G+1)(1+I)   (one rcp per 2 units)
//   o*tanh(cn) = (E-1) / [(E+1)(1+O)],    E=2^(2 L2E cn) (one rcp per 2 units)
// Round-6 vs round-4: __launch_bounds__(256,1) (full 512-VGPR budget; round
// 2-5 all pegged VGPR=76-84 < the 140-value live set -> weights were being
// remat-reloaded/AGPR-parked each iteration), and the exp2 overflow guard
// dropped (|c| <= 1/(1-sigma(1.2)) ~ 4.4 -> yE <= 13 << 128, provably safe).

#define T_LEN 1000
#define WAVES 4     // waves per block
#define BPW   2     // batch elements per wave
#define L2E 1.44269504088896340736f

typedef float v2f __attribute__((ext_vector_type(2)));

static __device__ __forceinline__ float exp2r(float x) { return __builtin_amdgcn_exp2f(x); }
static __device__ __forceinline__ float rcpr (float x) { return __builtin_amdgcn_rcpf(x); }
static __device__ __forceinline__ v2f fma2(v2f a, v2f b, v2f c) {
    return __builtin_elementwise_fma(a, b, c);
}
static __device__ __forceinline__ v2f splat2(float s) { v2f r; r.x = s; r.y = s; return r; }
static __device__ __forceinline__ v2f swap2(v2f a) { return __builtin_shufflevector(a, a, 1, 0); }

template<int CTRL>
static __device__ __forceinline__ float dpp0(float x) {
    return __int_as_float(__builtin_amdgcn_update_dpp(
        0, __float_as_int(x), CTRL, 0xf, 0xf, true));
}
// sum across 64 lanes; result valid in lane 63
static __device__ __forceinline__ float wave_sum63(float x) {
    x += dpp0<0x111>(x);   // row_shr:1
    x += dpp0<0x112>(x);   // row_shr:2
    x += dpp0<0x114>(x);   // row_shr:4
    x += dpp0<0x118>(x);   // row_shr:8
    x += dpp0<0x142>(x);   // row_bcast:15
    x += dpp0<0x143>(x);   // row_bcast:31
    return x;
}
static __device__ __forceinline__ float lane63(float x) {
    return __int_as_float(__builtin_amdgcn_readlane(__float_as_int(x), 63));
}
static __device__ __forceinline__ float rdlane(float x, int l) {
    return __int_as_float(__builtin_amdgcn_readlane(__float_as_int(x), l));
}

struct CellW {
    v2f wi[2], wf[2], wg[2], wo[2];   // input weights (prescaled), pair p = units {lane+128p, lane+128p+64}
    v2f vi[2], vf[2], vg[2], vo[2];   // recurrent weights (prescaled)
    v2f bi[2], bf[2], bg[2], bo[2];   // biases (bih+bhh, prescaled)
    v2f wr[2];                        // projection row
};

static __device__ __forceinline__ void load_w(CellW& W, int lane,
        const float* __restrict__ Wih, const float* __restrict__ Whh,
        const float* __restrict__ bih, const float* __restrict__ bhh,
        const float* __restrict__ Whr) {
#pragma unroll
    for (int p = 0; p < 2; ++p) {
        int ua = lane + 128 * p;
        int ub = ua + 64;
        v2f t;
        t.x = Wih[ua];        t.y = Wih[ub];        W.wi[p] = t * (-L2E);
        t.x = Wih[256 + ua];  t.y = Wih[256 + ub];  W.wf[p] = t * (-L2E);
        t.x = Wih[512 + ua];  t.y = Wih[512 + ub];  W.wg[p] = t * (2.0f * L2E);
        t.x = Wih[768 + ua];  t.y = Wih[768 + ub];  W.wo[p] = t * (-L2E);
        t.x = Whh[ua];        t.y = Whh[ub];        W.vi[p] = t * (-L2E);
        t.x = Whh[256 + ua];  t.y = Whh[256 + ub];  W.vf[p] = t * (-L2E);
        t.x = Whh[512 + ua];  t.y = Whh[512 + ub];  W.vg[p] = t * (2.0f * L2E);
        t.x = Whh[768 + ua];  t.y = Whh[768 + ub];  W.vo[p] = t * (-L2E);
        t.x = bih[ua] + bhh[ua];
        t.y = bih[ub] + bhh[ub];                    W.bi[p] = t * (-L2E);
        t.x = bih[256 + ua] + bhh[256 + ua];
        t.y = bih[256 + ub] + bhh[256 + ub];        W.bf[p] = t * (-L2E);
        t.x = bih[512 + ua] + bhh[512 + ua];
        t.y = bih[512 + ub] + bhh[512 + ub];        W.bg[p] = t * (2.0f * L2E);
        t.x = bih[768 + ua] + bhh[768 + ua];
        t.y = bih[768 + ub] + bhh[768 + ub];        W.bo[p] = t * (-L2E);
        t.x = Whr[ua];        t.y = Whr[ub];        W.wr[p] = t;
    }
}

// One LSTM cell step for this lane's 4 units (2 packed pairs). x,h wave-uniform.
static __device__ __forceinline__ float cell(const CellW& W, float x, float h,
                                             v2f (&c)[2]) {
    float s = 0.0f;
    const v2f xs = splat2(x);
    const v2f hs = splat2(h);
#pragma unroll
    for (int p = 0; p < 2; ++p) {
        v2f yi = fma2(xs, W.wi[p], fma2(hs, W.vi[p], W.bi[p]));
        v2f yf = fma2(xs, W.wf[p], fma2(hs, W.vf[p], W.bf[p]));
        v2f yg = fma2(xs, W.wg[p], fma2(hs, W.vg[p], W.bg[p]));
        v2f yo = fma2(xs, W.wo[p], fma2(hs, W.vo[p], W.bo[p]));
        v2f I, F, G, O;
        I.x = exp2r(yi.x); I.y = exp2r(yi.y);
        F.x = exp2r(yf.x); F.y = exp2r(yf.y);
        G.x = exp2r(yg.x); G.y = exp2r(yg.y);
        O.x = exp2r(yo.x); O.y = exp2r(yo.y);
        v2f w1  = F + 1.0f;
        v2f u   = (G + 1.0f) * (I + 1.0f);
        v2f num = fma2(u, c[p], (G - 1.0f) * w1);
        v2f D   = w1 * u;                          // per-unit denominator
        float rP = rcpr(D.x * D.y);                // merged rcp (pair)
        v2f cn  = (num * swap2(D)) * splat2(rP);
        c[p] = cn;
        v2f yE = cn * splat2(2.0f * L2E);          // |c|<=~4.4 -> no overflow
        v2f E;
        E.x = exp2r(yE.x);
        E.y = exp2r(yE.y);
        v2f d = (E + 1.0f) * (O + 1.0f);
        float rQ = rcpr(d.x * d.y);                // merged rcp (pair)
        v2f q = ((E - 1.0f) * W.wr[p]) * swap2(d);
        s = fmaf(q.x + q.y, rQ, s);
    }
    return s;
}

__global__ __launch_bounds__(256, 1)
void voltage_lstm_kernel(const float* __restrict__ x,
        const float* __restrict__ Wih0, const float* __restrict__ Whh0,
        const float* __restrict__ bih0, const float* __restrict__ bhh0,
        const float* __restrict__ Whr0,
        const float* __restrict__ Wih1, const float* __restrict__ Whh1,
        const float* __restrict__ bih1, const float* __restrict__ bhh1,
        const float* __restrict__ Whr1,
        const float* __restrict__ W1, const float* __restrict__ b1p,
        const float* __restrict__ W2, const float* __restrict__ b2,
        float* __restrict__ out)
{
    __shared__ __align__(16) float h1buf[WAVES][BPW][T_LEN];

    const int lane = threadIdx.x & 63;
    const int wv   = threadIdx.x >> 6;
    const int w    = blockIdx.x * WAVES + wv;
    const int bA   = w * BPW;
    const int bB   = bA + 1;

    CellW W0c, W1c;
    load_w(W0c, lane, Wih0, Whh0, bih0, bhh0, Whr0);
    load_w(W1c, lane, Wih1, Whh1, bih1, bhh1, Whr1);

    v2f c0A[2], c0B[2], c1A[2], c1B[2];
#pragma unroll
    for (int p = 0; p < 2; ++p) {
        c0A[p] = splat2(0.f); c0B[p] = splat2(0.f);
        c1A[p] = splat2(0.f); c1B[p] = splat2(0.f);
    }

    const float* xA = x + (long)bA * T_LEN;
    const float* xB = x + (long)bB * T_LEN;
    float xcA = xA[lane];              // x chunk for t in [0,64)
    float xcB = xB[lane];

    // --- prologue: layer0 step 0 (h0=0) ---
    float h0A, h0B, h1A = 0.0f, h1B = 0.0f;
    {
        float xtA = rdlane(xcA, 0), xtB = rdlane(xcB, 0);
        float sA = wave_sum63(cell(W0c, xtA, 0.0f, c0A));
        float sB = wave_sum63(cell(W0c, xtB, 0.0f, c0B));
        h0A = lane63(sA);
        h0B = lane63(sB);
    }

    // --- main loop: iter j computes layer0 step j+1 AND layer1 step j
    // (4 independent cell chains across 2 batches -> ILP).
    for (int j = 0; j < T_LEN - 1; ++j) {
        const int idx = j + 1;
        if ((idx & 63) == 0) {
            int tl = idx + lane;
            xcA = (tl < T_LEN) ? xA[tl] : 0.0f;
            xcB = (tl < T_LEN) ? xB[tl] : 0.0f;
        }
        float xtA = rdlane(xcA, idx & 63);
        float xtB = rdlane(xcB, idx & 63);

        float a0A = cell(W0c, xtA, h0A, c0A);
        float a0B = cell(W0c, xtB, h0B, c0B);
        float a1A = cell(W1c, h0A, h1A, c1A);
        float a1B = cell(W1c, h0B, h1B, c1B);

        a0A = wave_sum63(a0A);
        a0B = wave_sum63(a0B);
        a1A = wave_sum63(a1A);
        a1B = wave_sum63(a1B);

        if (lane == 63) {
            h1buf[wv][0][j] = a1A;
            h1buf[wv][1][j] = a1B;
        }
        h0A = lane63(a0A);  h0B = lane63(a0B);
        h1A = lane63(a1A);  h1B = lane63(a1B);
    }
    // --- epilogue: layer1 step T-1 ---
    {
        float a1A = wave_sum63(cell(W1c, h0A, h1A, c1A));
        float a1B = wave_sum63(cell(W1c, h0B, h1B, c1B));
        if (lane == 63) {
            h1buf[wv][0][T_LEN - 1] = a1A;
            h1buf[wv][1][T_LEN - 1] = a1B;
        }
    }
    __syncthreads();

    // --- head: relu(h1 @ W1^T + b1) @ W2^T + b2 for both batches ---
    const float* hA = h1buf[wv][0];
    const float* hB = h1buf[wv][1];
    const int j0 = lane;                 // rows 0..63
    const int j1 = lane + 64;            // rows 64..99 (lanes 0..35)
    const bool has1 = (j1 < 100);
    const float* r0 = W1 + j0 * T_LEN;
    const float* r1 = W1 + (has1 ? j1 : 0) * T_LEN;
    float aA0 = 0.f, aA1 = 0.f, aB0 = 0.f, aB1 = 0.f;
    for (int t = 0; t < T_LEN; t += 4) {
        float4 u0 = *(const float4*)(r0 + t);
        float4 u1 = *(const float4*)(r1 + t);
        float4 pA = *(const float4*)(hA + t);
        float4 pB = *(const float4*)(hB + t);
        aA0 = fmaf(u0.x, pA.x, aA0); aA0 = fmaf(u0.y, pA.y, aA0);
        aA0 = fmaf(u0.z, pA.z, aA0); aA0 = fmaf(u0.w, pA.w, aA0);
        aA1 = fmaf(u1.x, pA.x, aA1); aA1 = fmaf(u1.y, pA.y, aA1);
        aA1 = fmaf(u1.z, pA.z, aA1); aA1 = fmaf(u1.w, pA.w, aA1);
        aB0 = fmaf(u0.x, pB.x, aB0); aB0 = fmaf(u0.y, pB.y, aB0);
        aB0 = fmaf(u0.z, pB.z, aB0); aB0 = fmaf(u0.w, pB.w, aB0);
        aB1 = fmaf(u1.x, pB.x, aB1); aB1 = fmaf(u1.y, pB.y, aB1);
        aB1 = fmaf(u1.z, pB.z, aB1); aB1 = fmaf(u1.w, pB.w, aB1);
    }
    float bb0 = b1p[j0],   w20 = W2[j0];
    float bb1 = has1 ? b1p[j1] : 0.f;
    float w21 = has1 ? W2[j1]  : 0.f;
    float sA = fmaxf(aA0 + bb0, 0.f) * w20;
    float sB = fmaxf(aB0 + bb0, 0.f) * w20;
    if (has1) {
        sA = fmaf(fmaxf(aA1 + bb1, 0.f), w21, sA);
        sB = fmaf(fmaxf(aB1 + bb1, 0.f), w21, sB);
    }
    sA = wave_sum63(sA);
    sB = wave_sum63(sB);
    if (lane == 63) {
        float bias2 = b2[0];
        out[bA] = sA + bias2;
        out[bB] = sB + bias2;
    }
}

extern "C" void kernel_launch(void* const* d_in, const int* in_sizes, int n_in,
                              void* d_out, int out_size, void* d_ws, size_t ws_size,
                              hipStream_t stream) {
    (void)in_sizes; (void)n_in; (void)d_ws; (void)ws_size; (void)out_size;
    const float* x    = (const float*)d_in[0];
    const float* Wih0 = (const float*)d_in[1];
    const float* Whh0 = (const float*)d_in[2];
    const float* bih0 = (const float*)d_in[3];
    const float* bhh0 = (const float*)d_in[4];
    const float* Whr0 = (const float*)d_in[5];
    const float* Wih1 = (const float*)d_in[6];
    const float* Whh1 = (const float*)d_in[7];
    const float* bih1 = (const float*)d_in[8];
    const float* bhh1 = (const float*)d_in[9];
    const float* Whr1 = (const float*)d_in[10];
    const float* W1   = (const float*)d_in[11];
    const float* b1   = (const float*)d_in[12];
    const float* W2   = (const float*)d_in[13];
    const float* b2   = (const float*)d_in[14];
    float* outp = (float*)d_out;

    dim3 grid(16384 / (WAVES * BPW)), block(256);
    voltage_lstm_kernel<<<grid, block, 0, stream>>>(
        x, Wih0, Whh0, bih0, bhh0, Whr0,
        Wih1, Whh1, bih1, bhh1, Whr1,
        W1, b1, W2, b2, outp);
}